// Round 1
// baseline (239.256 us; speedup 1.0000x reference)
//
#include <hip/hip_runtime.h>
#include <hip/hip_bf16.h>

typedef __attribute__((ext_vector_type(8))) short short8;   // 8 bf16 (4 VGPRs)
typedef __attribute__((ext_vector_type(4))) float f32x4;    // MFMA C/D

#define L_SEQ 4096
#define DM    1024
#define DA    128   // d_attn == d_mid

// fp32 -> bf16 round-to-nearest-even
__device__ __forceinline__ short f2bf(float f) {
    union { float f; unsigned u; } v; v.f = f;
    unsigned u = v.u;
    u += 0x7FFFu + ((u >> 16) & 1u);
    return (short)(u >> 16);
}

// ---------------------------------------------------------------------------
// Kernel 1: QKV projection.  grid = (64, 3), block = 256.
// which==0: q = x@Wq + bq -> qb[L][128] bf16
// which==1: k = z@Wk + bk -> kb[L][128] bf16
// which==2: v = z@Wv + bv -> vT[128][L] bf16   (transposed for PV B-operand)
// ---------------------------------------------------------------------------
#define PBM 64
#define PBK 32
#define PLDA 40   // padded LDS row stride (shorts): breaks pow-2 bank stride
#define PLDB 40

__global__ __launch_bounds__(256) void qkv_proj_kernel(
    const float* __restrict__ x, const float* __restrict__ z,
    const float* __restrict__ Wq, const float* __restrict__ bq,
    const float* __restrict__ Wk, const float* __restrict__ bk,
    const float* __restrict__ Wv, const float* __restrict__ bv,
    short* __restrict__ qb, short* __restrict__ kb, short* __restrict__ vT)
{
    const int which = blockIdx.y;
    const float* __restrict__ Am   = (which == 0) ? x  : z;
    const float* __restrict__ W    = (which == 0) ? Wq : (which == 1) ? Wk : Wv;
    const float* __restrict__ bias = (which == 0) ? bq : (which == 1) ? bk : bv;

    __shared__ __align__(16) short As[PBM * PLDA];   // As[row][k]  64x32 (pad 40)
    __shared__ __align__(16) short Bs[DA  * PLDB];   // Bs[n][k]   128x32 (pad 40)

    const int t    = threadIdx.x;
    const int wave = t >> 6;
    const int lane = t & 63;
    const int l16  = lane & 15;
    const int quad = lane >> 4;
    const int row0 = blockIdx.x * PBM;

    f32x4 acc[8];
#pragma unroll
    for (int i = 0; i < 8; i++) acc[i] = (f32x4){0.f, 0.f, 0.f, 0.f};

    const int arow = t >> 2, aseg = t & 3;   // A staging: 64 rows x 32 k
    const int bn   = t >> 1, bkh  = t & 1;   // B staging: 128 n x 32 k (transpose)

#pragma unroll 1
    for (int k0 = 0; k0 < DM; k0 += PBK) {
        // ---- stage A tile (fp32 -> bf16) ----
        {
            const float* src = Am + (size_t)(row0 + arow) * DM + k0 + aseg * 8;
            f32x4 f0 = *(const f32x4*)src;
            f32x4 f1 = *(const f32x4*)(src + 4);
            short8 pk;
            pk[0] = f2bf(f0[0]); pk[1] = f2bf(f0[1]); pk[2] = f2bf(f0[2]); pk[3] = f2bf(f0[3]);
            pk[4] = f2bf(f1[0]); pk[5] = f2bf(f1[1]); pk[6] = f2bf(f1[2]); pk[7] = f2bf(f1[3]);
            *(short8*)&As[arow * PLDA + aseg * 8] = pk;
        }
        // ---- stage B tile transposed: Bs[n][k] = W[k0+k][n] ----
        {
            const float* wsrc = W + (size_t)(k0 + bkh * 16) * DA + bn;
            short8 b0, b1;
#pragma unroll
            for (int j = 0; j < 8; j++) b0[j] = f2bf(wsrc[(size_t)j * DA]);
#pragma unroll
            for (int j = 0; j < 8; j++) b1[j] = f2bf(wsrc[(size_t)(8 + j) * DA]);
            *(short8*)&Bs[bn * PLDB + bkh * 16]     = b0;
            *(short8*)&Bs[bn * PLDB + bkh * 16 + 8] = b1;
        }
        __syncthreads();

        // ---- MFMA: wave w computes rows [w*16, w*16+16) x all 128 cols ----
        // A-frag: A[m=l16][k=quad*8+j]; B-frag: B[k=quad*8+j][n=l16]
        short8 a = *(const short8*)&As[(wave * 16 + l16) * PLDA + quad * 8];
#pragma unroll
        for (int nt = 0; nt < 8; nt++) {
            short8 b = *(const short8*)&Bs[(nt * 16 + l16) * PLDB + quad * 8];
            acc[nt] = __builtin_amdgcn_mfma_f32_16x16x32_bf16(a, b, acc[nt], 0, 0, 0);
        }
        __syncthreads();
    }

    // ---- epilogue: bias add, bf16 store.  C layout: row=quad*4+r, col=l16 ----
#pragma unroll
    for (int nt = 0; nt < 8; nt++) {
        const int gcol = nt * 16 + l16;
        const float bv_ = bias[gcol];
#pragma unroll
        for (int r = 0; r < 4; r++) {
            const int grow = row0 + wave * 16 + quad * 4 + r;
            const short o = f2bf(acc[nt][r] + bv_);
            if (which == 0)      qb[(size_t)grow * DA + gcol] = o;
            else if (which == 1) kb[(size_t)grow * DA + gcol] = o;
            else                 vT[(size_t)gcol * L_SEQ + grow] = o;
        }
    }
}

// ---------------------------------------------------------------------------
// Kernel 2: flash attention.  grid = 256, block = 256 (4 waves).
// Block owns 16 q rows; wave w owns z in [w*1024, (w+1)*1024), BN=64 tiles.
// Partial (m, l, O) merged across waves via LDS at the end.
// ---------------------------------------------------------------------------
#define ABN 64

__global__ __launch_bounds__(256) void attn_kernel(
    const short* __restrict__ qb, const short* __restrict__ kb,
    const short* __restrict__ vT, float* __restrict__ out)
{
    __shared__ __align__(16) short qs[16 * 136];        // q tile, padded stride
    __shared__ __align__(16) short Ps[4][16 * 72];      // per-wave P round-trip
    __shared__ float Om[4][16][128];                     // per-wave O partials
    __shared__ float Ml[4][16], Ll[4][16];

    const int t    = threadIdx.x;
    const int wave = t >> 6;
    const int lane = t & 63;
    const int l16  = lane & 15;
    const int quad = lane >> 4;
    const int qr0  = blockIdx.x * 16;

    // stage q tile: 16 rows x 128 cols bf16
    {
        const int row = t >> 4, seg = t & 15;
        *(short8*)&qs[row * 136 + seg * 8] =
            *(const short8*)&qb[(size_t)(qr0 + row) * DA + seg * 8];
    }
    __syncthreads();

    // hoisted A-fragments of q (constant across the whole z loop)
    short8 afrag[4];
#pragma unroll
    for (int ks = 0; ks < 4; ks++)
        afrag[ks] = *(const short8*)&qs[l16 * 136 + ks * 32 + quad * 8];

    f32x4 O[8];
#pragma unroll
    for (int i = 0; i < 8; i++) O[i] = (f32x4){0.f, 0.f, 0.f, 0.f};
    float m_i[4], l_i[4];
#pragma unroll
    for (int r = 0; r < 4; r++) { m_i[r] = -1e30f; l_i[r] = 0.f; }

    const float scale = 0.08838834764831845f;  // 1/sqrt(128)
    const int z0 = wave * 1024;
    short* P = &Ps[wave][0];

#pragma unroll 1
    for (int it = 0; it < 16; it++) {
        const int zb = z0 + it * ABN;

        // ---- S = (q @ k^T): 4 n-tiles of 16x16, K=128 in 4 MFMA steps ----
        f32x4 s[4];
#pragma unroll
        for (int nt = 0; nt < 4; nt++) s[nt] = (f32x4){0.f, 0.f, 0.f, 0.f};
#pragma unroll
        for (int nt = 0; nt < 4; nt++) {
            const short* kp = kb + (size_t)(zb + nt * 16 + l16) * DA + quad * 8;
#pragma unroll
            for (int ks = 0; ks < 4; ks++) {
                short8 b = *(const short8*)(kp + ks * 32);
                s[nt] = __builtin_amdgcn_mfma_f32_16x16x32_bf16(afrag[ks], b, s[nt], 0, 0, 0);
            }
        }

        // ---- online softmax.  lane holds S[row=quad*4+r][col=nt*16+l16] ----
#pragma unroll
        for (int nt = 0; nt < 4; nt++)
#pragma unroll
            for (int r = 0; r < 4; r++) s[nt][r] *= scale;

        float rm[4];
#pragma unroll
        for (int r = 0; r < 4; r++)
            rm[r] = fmaxf(fmaxf(s[0][r], s[1][r]), fmaxf(s[2][r], s[3][r]));
#pragma unroll
        for (int off = 1; off < 16; off <<= 1)
#pragma unroll
            for (int r = 0; r < 4; r++)
                rm[r] = fmaxf(rm[r], __shfl_xor(rm[r], off));

        float mn[4], alpha[4], rs[4];
#pragma unroll
        for (int r = 0; r < 4; r++) {
            mn[r] = fmaxf(m_i[r], rm[r]);
            alpha[r] = __expf(m_i[r] - mn[r]);
            rs[r] = 0.f;
        }
#pragma unroll
        for (int nt = 0; nt < 4; nt++)
#pragma unroll
            for (int r = 0; r < 4; r++) {
                const float p = __expf(s[nt][r] - mn[r]);
                s[nt][r] = p;
                rs[r] += p;
            }
#pragma unroll
        for (int off = 1; off < 16; off <<= 1)
#pragma unroll
            for (int r = 0; r < 4; r++)
                rs[r] += __shfl_xor(rs[r], off);
#pragma unroll
        for (int r = 0; r < 4; r++) {
            l_i[r] = l_i[r] * alpha[r] + rs[r];
            m_i[r] = mn[r];
        }
#pragma unroll
        for (int nt = 0; nt < 8; nt++)
#pragma unroll
            for (int r = 0; r < 4; r++) O[nt][r] *= alpha[r];

        // ---- P (C layout) -> LDS in A-operand layout (per-wave private) ----
#pragma unroll
        for (int nt = 0; nt < 4; nt++)
#pragma unroll
            for (int r = 0; r < 4; r++)
                P[(quad * 4 + r) * 72 + nt * 16 + l16] = f2bf(s[nt][r]);
        __threadfence_block();  // lgkmcnt drain: DS writes visible before reads

        // ---- O += P @ V: A=P from LDS, B=V from global vT (z-contiguous) ----
#pragma unroll
        for (int ks2 = 0; ks2 < 2; ks2++) {
            short8 a2 = *(const short8*)&P[l16 * 72 + ks2 * 32 + quad * 8];
            const short* vp = vT + (size_t)l16 * L_SEQ + zb + ks2 * 32 + quad * 8;
#pragma unroll
            for (int nt = 0; nt < 8; nt++) {
                short8 b2 = *(const short8*)(vp + (size_t)(nt * 16) * L_SEQ);
                O[nt] = __builtin_amdgcn_mfma_f32_16x16x32_bf16(a2, b2, O[nt], 0, 0, 0);
            }
        }
    }

    // ---- write per-wave partials, merge across the 4 waves ----
#pragma unroll
    for (int nt = 0; nt < 8; nt++)
#pragma unroll
        for (int r = 0; r < 4; r++)
            Om[wave][quad * 4 + r][nt * 16 + l16] = O[nt][r];
    if (l16 == 0) {
#pragma unroll
        for (int r = 0; r < 4; r++) {
            Ml[wave][quad * 4 + r] = m_i[r];
            Ll[wave][quad * 4 + r] = l_i[r];
        }
    }
    __syncthreads();

    {
        const int row = t >> 4, cs = (t & 15) * 8;
        const float m0 = Ml[0][row], m1 = Ml[1][row], m2 = Ml[2][row], m3 = Ml[3][row];
        const float mf = fmaxf(fmaxf(m0, m1), fmaxf(m2, m3));
        const float e0 = __expf(m0 - mf), e1 = __expf(m1 - mf);
        const float e2 = __expf(m2 - mf), e3 = __expf(m3 - mf);
        const float lf = Ll[0][row] * e0 + Ll[1][row] * e1 + Ll[2][row] * e2 + Ll[3][row] * e3;
        const float inv = 1.f / lf;
        float* op = out + (size_t)(qr0 + row) * DA + cs;
#pragma unroll
        for (int j = 0; j < 8; j++) {
            const float a = Om[0][row][cs + j] * e0 + Om[1][row][cs + j] * e1 +
                            Om[2][row][cs + j] * e2 + Om[3][row][cs + j] * e3;
            op[j] = a * inv;
        }
    }
}

// ---------------------------------------------------------------------------
extern "C" void kernel_launch(void* const* d_in, const int* in_sizes, int n_in,
                              void* d_out, int out_size, void* d_ws, size_t ws_size,
                              hipStream_t stream) {
    (void)in_sizes; (void)n_in; (void)out_size; (void)ws_size;
    const float* x  = (const float*)d_in[0];
    const float* z  = (const float*)d_in[1];
    const float* Wq = (const float*)d_in[2];
    const float* bq = (const float*)d_in[3];
    const float* Wk = (const float*)d_in[4];
    const float* bk = (const float*)d_in[5];
    const float* Wv = (const float*)d_in[6];
    const float* bv = (const float*)d_in[7];
    float* out = (float*)d_out;

    short* qb = (short*)d_ws;                 // [4096][128] bf16
    short* kb = qb + (size_t)L_SEQ * DA;      // [4096][128] bf16
    short* vT = kb + (size_t)L_SEQ * DA;      // [128][4096] bf16

    dim3 pgrid(L_SEQ / PBM, 3);
    qkv_proj_kernel<<<pgrid, 256, 0, stream>>>(x, z, Wq, bq, Wk, bk, Wv, bv, qb, kb, vT);
    attn_kernel<<<L_SEQ / 16, 256, 0, stream>>>(qb, kb, vT, out);
}